// Round 6
// baseline (50.493 us; speedup 1.0000x reference)
//
#include <hip/hip_runtime.h>

typedef __attribute__((ext_vector_type(8))) short short8v;
typedef __attribute__((ext_vector_type(4))) float float4v;

constexpr int BB = 64, SS = 512, HH = 768, LL = 9, NCHUNK = 16, CHUNK = 32;
constexpr int KSTEPS = 24;

// async global->LDS, 16B per lane, dest = wave-uniform base + lane*16
__device__ __forceinline__ void gl2lds16(const void* g, void* l) {
  __builtin_amdgcn_global_load_lds(
      (const __attribute__((address_space(1))) unsigned int*)(g),
      (__attribute__((address_space(3))) unsigned int*)(l), 16, 0, 0);
}

#define WAITV(N) asm volatile("s_waitcnt vmcnt(" #N ")" ::: "memory")

// ---------------------------------------------------------------------------
// Kernel 0: pack W^T into per-(kstep,lane) bf16 MFMA A-fragments (global, L2).
// Also zeroes numAcc[0..63] and out[0].
// ---------------------------------------------------------------------------
__global__ __launch_bounds__(64) void packW_kernel(
    const float* __restrict__ W, unsigned short* __restrict__ packedW,
    float* __restrict__ numAcc, float* __restrict__ out) {
  const int s = blockIdx.x;      // kstep 0..23
  const int l = threadIdx.x;     // lane 0..63
  const int label = l & 15;
  const int kb = l >> 4;
  union { unsigned short u[8]; short8v v; } P;
#pragma unroll
  for (int e = 0; e < 8; ++e) {
    int k = s * 32 + kb * 8 + e;
    float f = (label < LL) ? W[(size_t)k * LL + label] : 0.f;
    P.u[e] = (unsigned short)(__float_as_uint(f) >> 16);
  }
  *reinterpret_cast<short8v*>(packedW + ((size_t)(s * 64 + l)) * 8) = P.v;
  if (s == 0) {
    if (l < BB) numAcc[l] = 0.f;
    if (l == 0) out[0] = 0.f;
  }
}

// ---------------------------------------------------------------------------
// Kernel 1 (fused): per (b,c) block of 256 threads (4 waves):
//   1. Emissions via MFMA with deep async staging: hs tile (32 rows x 768 f32,
//      96 KB) streamed through a 32 KB LDS ping-pong (2 groups x 4 slices x
//      4 KB) via global_load_lds, counted vmcnt(4) waits, raw s_barriers.
//      Slice source addresses pre-swizzled (u ^= r&7); fragment ds_reads
//      apply the same XOR. Wave w: tile=w&1, k-parity p=w>>1 (steps s%2==p,
//      Wf frag idx s>>1). f32 partials reduced through LDS -> emLDS[32][9].
//   2. Waves 0-1: barrier-free 9x9 log-semiring chunk product (ds_bpermute),
//      c==0 carries alpha0 in row 0 -> chunkM global.
//      Wave 2: interior numerator terms -> atomicAdd(numAcc[b]).
// ---------------------------------------------------------------------------
__global__ __launch_bounds__(256, 4) void fused_kernel(
    const float* __restrict__ hs, const int* __restrict__ mask,
    const int* __restrict__ labels, const unsigned short* __restrict__ packedW,
    const float* __restrict__ bias, const float* __restrict__ st,
    const float* __restrict__ trans, float* __restrict__ chunkM,
    float* __restrict__ numAcc) {
  const int bc = blockIdx.x;
  const int b = bc >> 4;
  const int c = bc & 15;
  const int tid = threadIdx.x;
  const int wave = tid >> 6;
  const int lane = tid & 63;
  const int rc = lane & 15;
  const int kb = lane >> 4;

  __shared__ __align__(16) float4 ldsA4[2048];   // 32 KB: 8 slices x 256 f4
  __shared__ float emLDS[CHUNK * LL];
  __shared__ float4v pacc[2][64];

  const int R0 = b * SS + c * CHUNK;             // global row base of tile

  // ---- phase 1: emissions via MFMA with async-LDS pipeline ----
  const int tile = wave & 1, p = wave >> 1;

  // Wf fragments for this wave's 12 k-steps (s = 2i+p), L2-hot.
  const short8v* pw = reinterpret_cast<const short8v*>(packedW);
  short8v Wf[12];
#pragma unroll
  for (int i = 0; i < 12; ++i) Wf[i] = pw[(size_t)(2 * i + p) * 64 + lane];
  // Drain Wf loads so vmcnt counts ONLY slice ops below (exact N counting).
  asm volatile("s_waitcnt vmcnt(0)" ::: "memory");

  // Staging addresses: thread t covers (row = t>>3, unit = t&7), source unit
  // pre-swizzled so LDS[r][u] = global unit u^(r&7) of row r.
  const int srow = tid >> 3;
  const int swu = (tid & 7) ^ (srow & 7);
  const char* srcbase =
      (const char*)hs + (size_t)(R0 + srow) * (HH * 4) + (size_t)swu * 16;
  char* ldsbase = (char*)ldsA4 + wave * 1024;    // + lane*16 by HW

#define ISSUE_GROUP(gg)                                                   \
  do {                                                                    \
    _Pragma("unroll") for (int j = 0; j < 4; ++j) {                       \
      int ss = 4 * (gg) + j;                                              \
      gl2lds16(srcbase + (size_t)ss * 128, ldsbase + ((ss & 7) << 12));   \
    }                                                                     \
  } while (0)

  const int erc = rc & 7;
  float4v acc = {0.f, 0.f, 0.f, 0.f};

#define CONSUME_STEP(s_, wfi)                                             \
  do {                                                                    \
    int base_ = ((s_) & 7) * 256 + (tile * 16 + rc) * 8;                  \
    float4 a0 = ldsA4[base_ + ((2 * kb) ^ erc)];                          \
    float4 a1 = ldsA4[base_ + ((2 * kb + 1) ^ erc)];                      \
    union { unsigned u[4]; short8v v; } Bf_;                              \
    Bf_.u[0] = __builtin_amdgcn_perm(__float_as_uint(a0.y), __float_as_uint(a0.x), 0x07060302u); \
    Bf_.u[1] = __builtin_amdgcn_perm(__float_as_uint(a0.w), __float_as_uint(a0.z), 0x07060302u); \
    Bf_.u[2] = __builtin_amdgcn_perm(__float_as_uint(a1.y), __float_as_uint(a1.x), 0x07060302u); \
    Bf_.u[3] = __builtin_amdgcn_perm(__float_as_uint(a1.w), __float_as_uint(a1.z), 0x07060302u); \
    acc = __builtin_amdgcn_mfma_f32_16x16x32_bf16(Wf[wfi], Bf_.v, acc, 0, 0, 0); \
  } while (0)

#define GROUP(g, DO_ISSUE, NW)                                            \
  do {                                                                    \
    WAITV(NW);                                                            \
    __builtin_amdgcn_s_barrier();                                         \
    __builtin_amdgcn_sched_barrier(0);                                    \
    CONSUME_STEP(4 * (g) + p, 2 * (g));                                   \
    CONSUME_STEP(4 * (g) + p + 2, 2 * (g) + 1);                           \
    asm volatile("s_waitcnt lgkmcnt(0)" ::: "memory");                    \
    __builtin_amdgcn_sched_barrier(0);                                    \
    __builtin_amdgcn_s_barrier();                                         \
    if (DO_ISSUE) ISSUE_GROUP((g) + 2);                                   \
  } while (0)

  // Prologue: groups 0,1 in flight (8 slice ops/wave = 32 KB/block).
  ISSUE_GROUP(0);
  ISSUE_GROUP(1);
  GROUP(0, true, 4);
  GROUP(1, true, 4);
  GROUP(2, true, 4);
  GROUP(3, true, 4);
  GROUP(4, false, 4);
  GROUP(5, false, 0);

  if (wave >= 2) pacc[wave - 2][lane] = acc;
  __syncthreads();
  if (wave < 2) {
    float4v o = pacc[wave][lane];
    if (kb < 3) {
#pragma unroll
      for (int r = 0; r < 4; ++r) {
        int lbl = kb * 4 + r;  // D row = label
        if (lbl < LL)
          emLDS[(tile * 16 + rc) * LL + lbl] = acc[r] + o[r] + bias[lbl];
      }
    }
  }
  __syncthreads();

  // ---- phase 2: chunk log-semiring product (waves 0-1) / numerator (wave 2)
  const int* mkp = mask + b * SS + c * CHUNK;
  if (wave < 2) {
    bool valid;
    int q;
    if (wave == 0) { valid = lane < 63; q = valid ? lane : 0; }
    else           { valid = lane < 18; q = valid ? 63 + lane : 0; }
    const int i = q / 9, j = q % 9;
    const int rowbase = lane - j;

    int addr[9];
#pragma unroll
    for (int k = 0; k < 9; ++k) addr[k] = (rowbase + k) * 4;
    float tc[9];
#pragma unroll
    for (int k = 0; k < 9; ++k) tc[k] = trans[k * LL + j];
    float ev[CHUNK];
#pragma unroll
    for (int s = 0; s < CHUNK; ++s) ev[s] = emLDS[s * LL + j];
    int mv[CHUNK];
#pragma unroll
    for (int s = 0; s < CHUNK; ++s) mv[s] = mkp[s];

    float mij;
    if (c == 0 && i == 0) mij = st[j] + emLDS[j];        // alpha0[j]
    else                  mij = (i == j) ? 0.f : -1e30f; // identity row

#pragma unroll
    for (int s = 0; s < CHUNK; ++s) {
      float x[9];
      float m = -3e38f;
#pragma unroll
      for (int k = 0; k < 9; ++k) {
        x[k] = __int_as_float(
                   __builtin_amdgcn_ds_bpermute(addr[k], __float_as_int(mij))) +
               tc[k];
        m = fmaxf(m, x[k]);
      }
      float s2 = 0.f;
#pragma unroll
      for (int k = 0; k < 9; ++k) s2 += __expf(x[k] - m);
      float nxt = m + __logf(s2) + ev[s];
      bool apply = valid && (mv[s] != 0) && !(c == 0 && s == 0);
      mij = apply ? nxt : mij;
    }
    if (valid) chunkM[(size_t)bc * 81 + q] = mij;
  } else if (wave == 2) {
    float val = 0.f;
    if (lane < CHUNK) {
      const int* lab = labels + b * SS;
      int tg = c * CHUNK + lane;
      if (tg >= 1 && mkp[lane] != 0) {
        int lp = lab[tg - 1], lc = lab[tg];
        val = trans[lp * LL + lc] + emLDS[lane * LL + lc];
      }
      if (c == 0 && lane == 0) {
        int l0 = lab[0];
        val += st[l0] + emLDS[l0];
      }
    }
#pragma unroll
    for (int off = 32; off; off >>= 1) val += __shfl_xor(val, off);
    if (lane == 0) atomicAdd(numAcc + b, val);
  }
}

// ---------------------------------------------------------------------------
// Kernel 2: per batch: v = chunkM[b][0].row0 (alpha after chunk 0), fold 15
// matrices, denom = lse(v + end_trans); out += denom - end_term - numAcc[b].
// ---------------------------------------------------------------------------
__global__ __launch_bounds__(64) void final_kernel(
    const int* __restrict__ mask, const int* __restrict__ labels,
    const float* __restrict__ et, const float* __restrict__ chunkM,
    const float* __restrict__ numAcc, float* __restrict__ out) {
  const int b = blockIdx.x;
  const int lane = threadIdx.x;
  const float* Mb = chunkM + (size_t)b * NCHUNK * 81;

  float v = (lane < LL) ? Mb[lane] : 0.f;  // row 0 of chunk 0
  for (int c = 1; c < NCHUNK; ++c) {
    const float* M = Mb + c * 81;
    float vk[9];
#pragma unroll
    for (int k = 0; k < 9; ++k) vk[k] = __shfl(v, k);
    if (lane < LL) {
      float x[9];
      float m = -3e38f;
#pragma unroll
      for (int k = 0; k < 9; ++k) {
        x[k] = vk[k] + M[k * 9 + lane];
        m = fmaxf(m, x[k]);
      }
      float s = 0.f;
#pragma unroll
      for (int k = 0; k < 9; ++k) s += __expf(x[k] - m);
      v = m + __logf(s);
    }
  }

  float vj[9];
#pragma unroll
  for (int k = 0; k < 9; ++k) vj[k] = __shfl(v, k) + et[k];
  float m = -3e38f;
#pragma unroll
  for (int k = 0; k < 9; ++k) m = fmaxf(m, vj[k]);
  float s = 0.f;
#pragma unroll
  for (int k = 0; k < 9; ++k) s += __expf(vj[k] - m);
  float denom = m + __logf(s);

  const int* mk = mask + b * SS;
  int cnt = 0;
  for (int tt = lane; tt < SS; tt += 64) cnt += mk[tt];
#pragma unroll
  for (int off = 32; off; off >>= 1) cnt += __shfl_xor(cnt, off);

  if (lane == 0) {
    int last = cnt - 1;
    float etterm = et[labels[b * SS + last]];
    atomicAdd(out, denom - etterm - numAcc[b]);
  }
}

extern "C" void kernel_launch(void* const* d_in, const int* in_sizes, int n_in,
                              void* d_out, int out_size, void* d_ws, size_t ws_size,
                              hipStream_t stream) {
  const float* hs     = (const float*)d_in[0];
  const int*   mask   = (const int*)d_in[1];
  const int*   labels = (const int*)d_in[2];
  const float* W      = (const float*)d_in[3];
  const float* bias   = (const float*)d_in[4];
  const float* st     = (const float*)d_in[5];
  const float* et     = (const float*)d_in[6];
  const float* trans  = (const float*)d_in[7];

  float* chunkM = (float*)d_ws;                                  // 82944 f32
  unsigned short* packedW =
      (unsigned short*)(chunkM + (size_t)BB * NCHUNK * 81);      // 24*64*8 bf16
  float* numAcc = (float*)(packedW + (size_t)KSTEPS * 64 * 8);   // 64 f32
  float* out    = (float*)d_out;

  packW_kernel<<<KSTEPS, 64, 0, stream>>>(W, packedW, numAcc, out);
  fused_kernel<<<BB * NCHUNK, 256, 0, stream>>>(hs, mask, labels, packedW,
                                                bias, st, trans, chunkM, numAcc);
  final_kernel<<<BB, 64, 0, stream>>>(mask, labels, et, chunkM, numAcc, out);
}